// Round 7
// baseline (257.515 us; speedup 1.0000x reference)
//
#include <hip/hip_runtime.h>
#include <cstdint>
#include <cstddef>

// ---------------------------------------------------------------------------
// GCN 3-layer forward, CSR-gather formulation:
//   out[d] = dinv[d] * ( sum_{s in N(d)} T'[s] + T'[d] ) + b,
//   with T'[r] = dinv[r] * (X[r] @ W)   (scale fused into matmul epilogue).
// CSR build: 2-level bucket counting sort, all fine-grained atomics in LDS.
// Round 6: gather restructured for memory-level parallelism — each lane
// loads float4, a wave covers EPB=256/COUT edges per vmem instruction
// (4-deep unrolled -> 16-32 edges in flight vs 8), shfl_xor combine.
// ---------------------------------------------------------------------------

#define CH 4096      // edges per S1/S3 block
#define BSHIFT 9     // 512 dsts per bucket
#define BSIZE 512
// assumes n <= 131072 (src fits 17 bits, NB <= 256); n = 100000 here.

__device__ __forceinline__ int eidx_at(const void* p, long long i, int is64) {
  if (is64) return (int)((const long long*)p)[i];
  return ((const int*)p)[i];
}

__global__ void k_flag(const void* eidx, int* flag) {
  const unsigned long long* p = (const unsigned long long*)eidx;
  int lane = threadIdx.x & 63;
  int bad = 0;
#pragma unroll
  for (int i = 0; i < 4; ++i) bad |= (p[lane + 64 * i] > 1000000000ULL) ? 1 : 0;
  int any_bad = __any(bad);
  if (lane == 0) *flag = any_bad ? 0 : 1;
}

// S1: per-block histogram over buckets (LDS atomics only)
__global__ __launch_bounds__(256) void k_s1(const void* eidx, const int* flag,
                                            int* __restrict__ blk_off,
                                            int* __restrict__ bucket_tot,
                                            int E, int NB) {
  __shared__ int h[256];
  int t = threadIdx.x, blk = blockIdx.x;
  if (t < NB) h[t] = 0;
  __syncthreads();
  int is64 = *flag;
  int lo = blk * CH, hi = min(lo + CH, E);
  for (int i = lo + t; i < hi; i += 256) {
    int d = eidx_at(eidx, (long long)E + i, is64);
    atomicAdd(&h[d >> BSHIFT], 1);
  }
  __syncthreads();
  if (t < NB) {
    blk_off[(size_t)blk * NB + t] = h[t];
    atomicAdd(&bucket_tot[t], h[t]);
  }
}

// S2a: exclusive scan of bucket totals (NB <= 256)
__global__ __launch_bounds__(256) void k_s2a(const int* __restrict__ bucket_tot,
                                             int* __restrict__ bucket_base,
                                             int* __restrict__ rowptr,
                                             int NB, int n, int E) {
  int t = threadIdx.x;
  __shared__ int sh[256];
  int v = (t < NB) ? bucket_tot[t] : 0;
  sh[t] = v;
  __syncthreads();
  for (int off = 1; off < 256; off <<= 1) {
    int x = (t >= off) ? sh[t - off] : 0;
    __syncthreads();
    sh[t] += x;
    __syncthreads();
  }
  if (t < NB) bucket_base[t] = sh[t] - v;
  if (t == 0) { bucket_base[NB] = E; rowptr[n] = E; }
}

// S2b: per bucket, scan its per-block counts -> exclusive write ranges
__global__ __launch_bounds__(256) void k_s2b(int* __restrict__ blk_off,
                                             const int* __restrict__ bucket_base,
                                             int nblk, int NB) {
  int b = blockIdx.x, t = threadIdx.x;
  __shared__ int sh[256];
  __shared__ int carry;
  if (t == 0) carry = bucket_base[b];
  __syncthreads();
  for (int tile = 0; tile < nblk; tile += 256) {
    int i = tile + t;
    int v = (i < nblk) ? blk_off[(size_t)i * NB + b] : 0;
    sh[t] = v;
    __syncthreads();
    for (int off = 1; off < 256; off <<= 1) {
      int x = (t >= off) ? sh[t - off] : 0;
      __syncthreads();
      sh[t] += x;
      __syncthreads();
    }
    int c = carry;
    if (i < nblk) blk_off[(size_t)i * NB + b] = c + sh[t] - v;
    int tot = sh[255];
    __syncthreads();
    if (t == 0) carry = c + tot;
    __syncthreads();
  }
}

// S3: scatter packed edges into this block's disjoint bucket ranges
__global__ __launch_bounds__(256) void k_s3(const void* eidx, const int* flag,
                                            const int* __restrict__ blk_off,
                                            unsigned int* __restrict__ packed,
                                            int E, int NB) {
  __shared__ int cur[256];
  int t = threadIdx.x, blk = blockIdx.x;
  if (t < NB) cur[t] = blk_off[(size_t)blk * NB + t];
  __syncthreads();
  int is64 = *flag;
  int lo = blk * CH, hi = min(lo + CH, E);
  for (int i = lo + t; i < hi; i += 256) {
    int s = eidx_at(eidx, i, is64);
    int d = eidx_at(eidx, (long long)E + i, is64);
    int pos = atomicAdd(&cur[d >> BSHIFT], 1);  // LDS atomic
    packed[pos] = ((unsigned)(d & (BSIZE - 1)) << 17) | (unsigned)s;
  }
}

// S4: one block per bucket. LDS hist over 512 local dsts -> rowptr/dinv
// (coalesced), then scatter csr_src within the bucket's window.
__global__ __launch_bounds__(256) void k_s4(const unsigned int* __restrict__ packed,
                                            const int* __restrict__ bucket_base,
                                            int* __restrict__ rowptr,
                                            float* __restrict__ dinv,
                                            int* __restrict__ csr_src, int n) {
  int b = blockIdx.x, t = threadIdx.x;
  int lo = bucket_base[b], hi = bucket_base[b + 1];
  __shared__ int h[BSIZE];
  __shared__ int ps[256];
  __shared__ int cur[BSIZE];
  h[2 * t] = 0; h[2 * t + 1] = 0;
  __syncthreads();
  for (int i = lo + t; i < hi; i += 256)
    atomicAdd(&h[packed[i] >> 17], 1);
  __syncthreads();
  int a0 = h[2 * t], a1 = h[2 * t + 1];
  ps[t] = a0 + a1;
  __syncthreads();
  for (int off = 1; off < 256; off <<= 1) {
    int x = (t >= off) ? ps[t - off] : 0;
    __syncthreads();
    ps[t] += x;
    __syncthreads();
  }
  int pexcl = ps[t] - (a0 + a1);
  int e0 = lo + pexcl, e1 = lo + pexcl + a0;
  cur[2 * t] = e0;
  cur[2 * t + 1] = e1;
  int node0 = b * BSIZE + 2 * t, node1 = b * BSIZE + 2 * t + 1;
  if (node0 < n) { rowptr[node0] = e0; dinv[node0] = rsqrtf((float)(a0 + 1)); }
  if (node1 < n) { rowptr[node1] = e1; dinv[node1] = rsqrtf((float)(a1 + 1)); }
  __syncthreads();
  for (int i = lo + t; i < hi; i += 256) {
    unsigned p = packed[i];
    int j = p >> 17;
    int s = (int)(p & 0x1FFFFu);
    int pos = atomicAdd(&cur[j], 1);  // LDS atomic
    csr_src[pos] = s;
  }
}

// T'[r] = dinv[r] * (X[r] @ W).  One thread per row; W as float4 in LDS.
template <int COUT>
__global__ __launch_bounds__(256) void k_matmul(const float* __restrict__ X,
                                                const float* __restrict__ W,
                                                const float* __restrict__ dinv,
                                                float* __restrict__ T, int n) {
  const int C4 = COUT / 4;
  __shared__ float4 Ws[64 * C4];
  for (int i = threadIdx.x; i < 64 * C4; i += blockDim.x)
    Ws[i] = ((const float4*)W)[i];
  __syncthreads();
  int r = blockIdx.x * blockDim.x + threadIdx.x;
  if (r >= n) return;
  float4 acc[C4];
#pragma unroll
  for (int j = 0; j < C4; ++j) acc[j] = make_float4(0.f, 0.f, 0.f, 0.f);
  const float4* xr = (const float4*)(X + (size_t)r * 64);
#pragma unroll
  for (int k4 = 0; k4 < 16; ++k4) {
    float4 xv = xr[k4];
    const float xs[4] = {xv.x, xv.y, xv.z, xv.w};
#pragma unroll
    for (int c = 0; c < 4; ++c) {
      float xk = xs[c];
      const float4* wrow = &Ws[(k4 * 4 + c) * C4];
#pragma unroll
      for (int j = 0; j < C4; ++j) {
        float4 w = wrow[j];
        acc[j].x = fmaf(xk, w.x, acc[j].x);
        acc[j].y = fmaf(xk, w.y, acc[j].y);
        acc[j].z = fmaf(xk, w.z, acc[j].z);
        acc[j].w = fmaf(xk, w.w, acc[j].w);
      }
    }
  }
  float dr = dinv[r];
  float4* tr = (float4*)(T + (size_t)r * COUT);
#pragma unroll
  for (int j = 0; j < C4; ++j)
    tr[j] = make_float4(acc[j].x * dr, acc[j].y * dr, acc[j].z * dr, acc[j].w * dr);
}

// One wave per dst row, float4 per lane, EPB = 256/COUT edges per vmem
// instruction (lane = g*CPL + c: g = edge slot, c = feature chunk).
// 4-deep unroll -> up to 4*EPB edges in flight. shfl_xor combine at row end.
template <int COUT, bool RELU>
__global__ __launch_bounds__(256) void k_gather(const float* __restrict__ T,
                                                const int* __restrict__ rowptr,
                                                const int* __restrict__ csr_src,
                                                const float* __restrict__ dinv,
                                                const float* __restrict__ bias,
                                                float* __restrict__ out, int n) {
  const int CPL = COUT / 4;   // lanes per edge (each lane holds float4)
  const int EPB = 64 / CPL;   // edges per batch (4 @ COUT=64, 8 @ COUT=32)
  int wave = blockIdx.x * (blockDim.x >> 6) + (threadIdx.x >> 6);
  int lane = threadIdx.x & 63;
  int row = __builtin_amdgcn_readfirstlane(wave);
  if (row >= n) return;
  int beg = rowptr[row];
  int end = rowptr[row + 1];
  int g = lane / CPL;         // edge slot within batch
  int c = lane % CPL;         // feature chunk (floats 4c..4c+3)
  const float4* T4 = (const float4*)T;
  float4 a0 = make_float4(0.f, 0.f, 0.f, 0.f);
  float4 a1 = make_float4(0.f, 0.f, 0.f, 0.f);
  float4 a2 = make_float4(0.f, 0.f, 0.f, 0.f);
  float4 a3 = make_float4(0.f, 0.f, 0.f, 0.f);
  int j = beg;
  for (; j + 4 * EPB <= end; j += 4 * EPB) {
    int s0 = csr_src[j + 0 * EPB + g];
    int s1 = csr_src[j + 1 * EPB + g];
    int s2 = csr_src[j + 2 * EPB + g];
    int s3 = csr_src[j + 3 * EPB + g];
    float4 v0 = T4[(size_t)s0 * CPL + c];
    float4 v1 = T4[(size_t)s1 * CPL + c];
    float4 v2 = T4[(size_t)s2 * CPL + c];
    float4 v3 = T4[(size_t)s3 * CPL + c];
    a0.x += v0.x; a0.y += v0.y; a0.z += v0.z; a0.w += v0.w;
    a1.x += v1.x; a1.y += v1.y; a1.z += v1.z; a1.w += v1.w;
    a2.x += v2.x; a2.y += v2.y; a2.z += v2.z; a2.w += v2.w;
    a3.x += v3.x; a3.y += v3.y; a3.z += v3.z; a3.w += v3.w;
  }
  for (; j + EPB <= end; j += EPB) {
    int s = csr_src[j + g];
    float4 v = T4[(size_t)s * CPL + c];
    a0.x += v.x; a0.y += v.y; a0.z += v.z; a0.w += v.w;
  }
  if (j + g < end) {  // ragged tail: lanes g < remaining participate
    int s = csr_src[j + g];
    float4 v = T4[(size_t)s * CPL + c];
    a1.x += v.x; a1.y += v.y; a1.z += v.z; a1.w += v.w;
  }
  float4 acc;
  acc.x = (a0.x + a1.x) + (a2.x + a3.x);
  acc.y = (a0.y + a1.y) + (a2.y + a3.y);
  acc.z = (a0.z + a1.z) + (a2.z + a3.z);
  acc.w = (a0.w + a1.w) + (a2.w + a3.w);
#pragma unroll
  for (int m = CPL; m < 64; m <<= 1) {
    acc.x += __shfl_xor(acc.x, m, 64);
    acc.y += __shfl_xor(acc.y, m, 64);
    acc.z += __shfl_xor(acc.z, m, 64);
    acc.w += __shfl_xor(acc.w, m, 64);
  }
  float4 tr = T4[(size_t)row * CPL + c];   // self-loop term (broadcast-safe)
  float4 bb = ((const float4*)bias)[c];
  float dr = dinv[row];
  float4 o;
  o.x = fmaf(dr, acc.x + tr.x, bb.x);
  o.y = fmaf(dr, acc.y + tr.y, bb.y);
  o.z = fmaf(dr, acc.z + tr.z, bb.z);
  o.w = fmaf(dr, acc.w + tr.w, bb.w);
  if (RELU) {
    o.x = fmaxf(o.x, 0.f); o.y = fmaxf(o.y, 0.f);
    o.z = fmaxf(o.z, 0.f); o.w = fmaxf(o.w, 0.f);
  }
  if (g == 0) ((float4*)out)[(size_t)row * CPL + c] = o;
}

extern "C" void kernel_launch(void* const* d_in, const int* in_sizes, int n_in,
                              void* d_out, int out_size, void* d_ws, size_t ws_size,
                              hipStream_t stream) {
  const float* x  = (const float*)d_in[0];
  const void*  ei = d_in[1];
  const float* W1 = (const float*)d_in[2];
  const float* b1 = (const float*)d_in[3];
  const float* W2 = (const float*)d_in[4];
  const float* b2 = (const float*)d_in[5];
  const float* W3 = (const float*)d_in[6];
  const float* b3 = (const float*)d_in[7];
  float* out = (float*)d_out;

  const int n = in_sizes[0] / 64;   // 100000
  const int E = in_sizes[1] / 2;    // 1000000

  const int NB   = (n + BSIZE - 1) / BSIZE;  // 196 buckets
  const int NBLK = (E + CH - 1) / CH;        // 245 edge blocks

  char* ws = (char*)d_ws;
  size_t off = 0;
  auto carve = [&](size_t bytes) -> void* {
    void* p = ws + off;
    off = (off + bytes + 255) & ~(size_t)255;
    return p;
  };
  int*      flag        = (int*)carve(16);
  float*    dinv        = (float*)carve(sizeof(float) * n);
  int*      rowptr      = (int*)carve(sizeof(int) * (n + 1));
  int*      bucket_tot  = (int*)carve(sizeof(int) * 256);
  int*      bucket_base = (int*)carve(sizeof(int) * 257);
  int*      blk_off     = (int*)carve(sizeof(int) * (size_t)NBLK * NB);
  unsigned* packed      = (unsigned*)carve(sizeof(unsigned) * E);
  int*      csr_src     = (int*)carve(sizeof(int) * E);
  float*    T           = (float*)carve(sizeof(float) * (size_t)n * 64);
  float*    A           = (float*)carve(sizeof(float) * (size_t)n * 64);

  const int B = 256;
  const int gN = (n + B - 1) / B;
  const int gW = (n + 3) / 4;  // 4 waves/block, 1 wave/row

  // ---- CSR build (bucket counting sort; no global fine-grained atomics) ----
  k_flag<<<1, 64, 0, stream>>>(ei, flag);
  hipMemsetAsync(bucket_tot, 0, sizeof(int) * NB, stream);
  k_s1<<<NBLK, B, 0, stream>>>(ei, flag, blk_off, bucket_tot, E, NB);
  k_s2a<<<1, B, 0, stream>>>(bucket_tot, bucket_base, rowptr, NB, n, E);
  k_s2b<<<NB, B, 0, stream>>>(blk_off, bucket_base, NBLK, NB);
  k_s3<<<NBLK, B, 0, stream>>>(ei, flag, blk_off, packed, E, NB);
  k_s4<<<NB, B, 0, stream>>>(packed, bucket_base, rowptr, dinv, csr_src, n);

  // ---- layer 1: x -> A ----
  k_matmul<64><<<gN, B, 0, stream>>>(x, W1, dinv, T, n);
  k_gather<64, true><<<gW, B, 0, stream>>>(T, rowptr, csr_src, dinv, b1, A, n);

  // ---- layer 2: A -> A ----
  k_matmul<64><<<gN, B, 0, stream>>>(A, W2, dinv, T, n);
  k_gather<64, true><<<gW, B, 0, stream>>>(T, rowptr, csr_src, dinv, b2, A, n);

  // ---- layer 3: A -> out ----
  k_matmul<32><<<gN, B, 0, stream>>>(A, W3, dinv, T, n);
  k_gather<32, false><<<gW, B, 0, stream>>>(T, rowptr, csr_src, dinv, b3, out, n);
}